// Round 3
// baseline (71.550 us; speedup 1.0000x reference)
//
#include <hip/hip_runtime.h>

#define FEAT 128
#define N_RR 512
#define N_MG 1024
#define N_NU 512
#define N_MU 512
#define N_BOX (N_RR + N_MG + N_NU + N_MU)   // 2560

__global__ __launch_bounds__(64) void bev_draw_kernel(
    const float* __restrict__ rr,   // (B,512,7)
    const float* __restrict__ rs,   // (B,512)
    const float* __restrict__ mg,   // (B,1024,8)
    const float* __restrict__ ms,   // (B,1024)
    const float* __restrict__ nu,   // (B,512,8)
    const float* __restrict__ mu,   // (B,512,8)
    float* __restrict__ out)        // (B,1,128,128)
{
    const float SCALE = 0.8f;       // VOXEL*OUT_FACTOR
    const float PC_MIN = -51.2f;

    int bid = blockIdx.x;
    int frame = bid / N_BOX;
    int b = bid - frame * N_BOX;

    float bx, by, bw, bl, val;
    if (b < N_RR) {
        const float* p = rr + ((size_t)frame * N_RR + b) * 7;
        bx = p[0]; by = p[1]; bw = p[3]; bl = p[4];
        val = rs[frame * N_RR + b];
    } else if (b < N_RR + N_MG) {
        int j = b - N_RR;
        const float* p = mg + ((size_t)frame * N_MG + j) * 8;
        bx = p[0]; by = p[1]; bw = p[3]; bl = p[4];
        int cls = (int)p[7];
        bool is_small = (cls == 5) | (cls == 6) | (cls == 8) | (cls == 9);
        val = is_small ? (ms[frame * N_MG + j] + 1.0f) * 0.5f : 0.5f;
    } else if (b < N_RR + N_MG + N_NU) {
        int j = b - (N_RR + N_MG);
        const float* p = nu + ((size_t)frame * N_NU + j) * 8;
        bx = p[0]; by = p[1]; bw = p[3]; bl = p[4];
        val = 0.4f;
    } else {
        int j = b - (N_RR + N_MG + N_NU);
        const float* p = mu + ((size_t)frame * N_MU + j) * 8;
        bx = p[0]; by = p[1]; bw = p[3]; bl = p[4];
        val = 0.2f;
    }

    // feature-map size + validity (f32 math to match reference)
    float w_fm = bw / SCALE;
    float l_fm = bl / SCALE;
    bool valid = (w_fm > 0.0f) & (l_fm > 0.0f) & (w_fm <= 1000.0f) & (l_fm <= 1000.0f);

    // gaussian_radius_vec(height=l_fm, width=w_fm, min_overlap=0.1)
    float h = l_fm, w = w_fm;
    float b1 = h + w;
    float c1 = w * h * (1.0f - 0.1f) / (1.0f + 0.1f);
    float r1 = (b1 + sqrtf(fmaxf(b1 * b1 - 4.0f * c1, 0.0f))) * 0.5f;
    float b2 = 2.0f * (h + w);
    float c2 = (1.0f - 0.1f) * w * h;
    float r2 = (b2 + sqrtf(fmaxf(b2 * b2 - 16.0f * c2, 0.0f))) * 0.5f;
    float b3 = -2.0f * 0.1f * (h + w);
    float c3 = (0.1f - 1.0f) * w * h;
    float r3 = (b3 + sqrtf(fmaxf(b3 * b3 - 16.0f * 0.1f * c3, 0.0f))) * 0.5f;
    float rf = fminf(fminf(r1, r2), r3);

    int ri = (int)rf;              // truncation, same as astype(int32)
    ri = ri < 2 ? 2 : ri;
    ri = ri > 32 ? 32 : ri;

    int cx = (int)((bx - PC_MIN) / SCALE);
    int cy = (int)((by - PC_MIN) / SCALE);
    valid = valid && (cx >= 0) && (cx < FEAT) && (cy >= 0) && (cy < FEAT);
    if (!valid || !(val > 0.0f)) return;   // zero contributions are no-ops vs 0-init

    float sigma = (float)(2 * ri + 1) / 6.0f;
    float inv_denom = 1.0f / (2.0f * sigma * sigma);
    int side = 2 * ri + 1;
    int npx = side * side;

    unsigned int* hm = (unsigned int*)out + (size_t)frame * FEAT * FEAT;

    for (int i = threadIdx.x; i < npx; i += 64) {
        int dy = i / side - ri;
        int dx = i - (dy + ri) * side - ri;
        int y = cy + dy;
        int x = cx + dx;
        if ((unsigned)y < FEAT && (unsigned)x < FEAT) {
            float g = __expf(-(float)(dx * dx + dy * dy) * inv_denom);
            float v = val * g;
            // non-negative floats: uint compare == float compare
            atomicMax(&hm[y * FEAT + x], __float_as_uint(v));
        }
    }
}

extern "C" void kernel_launch(void* const* d_in, const int* in_sizes, int n_in,
                              void* d_out, int out_size, void* d_ws, size_t ws_size,
                              hipStream_t stream) {
    const float* rr = (const float*)d_in[0];
    const float* rs = (const float*)d_in[1];
    const float* mg = (const float*)d_in[2];
    const float* ms = (const float*)d_in[3];
    const float* nu = (const float*)d_in[4];
    const float* mu = (const float*)d_in[5];
    float* out = (float*)d_out;

    int B = in_sizes[1] / N_RR;   // refined_scores is (B,512)

    // d_out is poisoned to 0xAA before every launch — zero it (graph-safe async op)
    hipMemsetAsync(d_out, 0, (size_t)out_size * sizeof(float), stream);

    dim3 grid(B * N_BOX);
    bev_draw_kernel<<<grid, 64, 0, stream>>>(rr, rs, mg, ms, nu, mu, out);
}